// Round 1
// baseline (847.207 us; speedup 1.0000x reference)
//
#include <hip/hip_runtime.h>

// Problem constants: B=4, S=2048, D=1024, H=16, DK=64
#define BB 4
#define SS 2048
#define DD 1024
#define HH 16
#define DKK 64
#define MTOT (BB * SS)   // 8192

typedef __attribute__((ext_vector_type(8))) short short8;     // 8 bf16 = 4 VGPR (MFMA A/B frag)
typedef __attribute__((ext_vector_type(4))) float f32x4;      // MFMA C/D frag
typedef __attribute__((ext_vector_type(4))) unsigned short u16x4;

typedef unsigned short ushort_t;

__device__ __forceinline__ ushort_t f2bf(float f) {
    union { float f; unsigned u; } c; c.f = f;
    unsigned r = c.u + 0x7fffu + ((c.u >> 16) & 1u);   // RNE; inputs are finite
    return (ushort_t)(r >> 16);
}

// ---------------------------------------------------------------------------
// GEMM: C[M,N] = A[M,K] * W[N,K]^T   (nn.Linear: x @ W^T)
// A is fp32 or bf16 (A_BF16), W is fp32, out is bf16 or fp32 (OUT_BF16).
// 128x128 tile, BK=32 (one 16x16x32 MFMA K-step), 4 waves, 64x64 per wave.
// fp32->bf16 conversion fused into LDS staging.
// ---------------------------------------------------------------------------
template<bool A_BF16, bool OUT_BF16>
__global__ __launch_bounds__(256, 2)
void gemm_bt(const void* __restrict__ Av, const float* __restrict__ W,
             void* __restrict__ Cv, int K, int N)
{
    __shared__ ushort_t As[128][40];   // +8 bf16 pad: 80B row stride, 16B aligned
    __shared__ ushort_t Bs[128][40];

    const int tid  = threadIdx.x;
    const int lane = tid & 63;
    const int w    = tid >> 6;
    const int wm   = w >> 1, wn = w & 1;
    const int l15  = lane & 15, l4 = lane >> 4;
    const int m0   = blockIdx.x * 128;
    const int n0   = blockIdx.y * 128;

    f32x4 acc[4][4] = {};

    for (int kk = 0; kk < K; kk += 32) {
        // ---- stage A tile (128 x 32) ----
        if constexpr (A_BF16) {
            const ushort_t* A = (const ushort_t*)Av;
            #pragma unroll
            for (int i = 0; i < 2; ++i) {
                int slot = tid + i * 256;                 // 0..511
                int row = slot >> 2, c = (slot & 3) * 8;  // 8 bf16 per chunk
                *(short8*)(&As[row][c]) =
                    *(const short8*)(A + (size_t)(m0 + row) * K + kk + c);
            }
        } else {
            const float* A = (const float*)Av;
            #pragma unroll
            for (int i = 0; i < 4; ++i) {
                int slot = tid + i * 256;                 // 0..1023
                int row = slot >> 3, c = (slot & 7) * 4;  // 4 fp32 per chunk
                f32x4 v = *(const f32x4*)(A + (size_t)(m0 + row) * K + kk + c);
                u16x4 h;
                h[0] = f2bf(v[0]); h[1] = f2bf(v[1]); h[2] = f2bf(v[2]); h[3] = f2bf(v[3]);
                *(u16x4*)(&As[row][c]) = h;
            }
        }
        // ---- stage W tile (128 x 32), always fp32 ----
        #pragma unroll
        for (int i = 0; i < 4; ++i) {
            int slot = tid + i * 256;
            int row = slot >> 3, c = (slot & 7) * 4;
            f32x4 v = *(const f32x4*)(W + (size_t)(n0 + row) * K + kk + c);
            u16x4 h;
            h[0] = f2bf(v[0]); h[1] = f2bf(v[1]); h[2] = f2bf(v[2]); h[3] = f2bf(v[3]);
            *(u16x4*)(&Bs[row][c]) = h;
        }
        __syncthreads();

        // ---- fragments + MFMA ----
        short8 af[4], bf[4];
        #pragma unroll
        for (int mi = 0; mi < 4; ++mi)
            af[mi] = *(const short8*)(&As[wm * 64 + mi * 16 + l15][l4 * 8]);
        #pragma unroll
        for (int ni = 0; ni < 4; ++ni)
            bf[ni] = *(const short8*)(&Bs[wn * 64 + ni * 16 + l15][l4 * 8]);
        #pragma unroll
        for (int mi = 0; mi < 4; ++mi)
            #pragma unroll
            for (int ni = 0; ni < 4; ++ni)
                acc[mi][ni] = __builtin_amdgcn_mfma_f32_16x16x32_bf16(
                    af[mi], bf[ni], acc[mi][ni], 0, 0, 0);
        __syncthreads();
    }

    // ---- epilogue: C/D layout col=lane&15, row=(lane>>4)*4+r ----
    #pragma unroll
    for (int mi = 0; mi < 4; ++mi) {
        int rowb = m0 + wm * 64 + mi * 16 + l4 * 4;
        #pragma unroll
        for (int ni = 0; ni < 4; ++ni) {
            int col = n0 + wn * 64 + ni * 16 + l15;
            #pragma unroll
            for (int r = 0; r < 4; ++r) {
                size_t off = (size_t)(rowb + r) * N + col;
                if constexpr (OUT_BF16) ((ushort_t*)Cv)[off] = f2bf(acc[mi][ni][r]);
                else                    ((float*)Cv)[off]    = acc[mi][ni][r];
            }
        }
    }
}

// ---------------------------------------------------------------------------
// Flash-style causal attention over projected bf16 Q/K/V [B,S,D] (head-major
// slice at h*64). 128 q-rows per block (32 per wave), k-tiles of 64, online
// softmax, P->LDS roundtrip (C-layout -> A-layout), V transposed in LDS.
// ---------------------------------------------------------------------------
__global__ __launch_bounds__(256, 2)
void attn_fwd(const ushort_t* __restrict__ Qp, const ushort_t* __restrict__ Kp,
              const ushort_t* __restrict__ Vp, ushort_t* __restrict__ Ctx)
{
    __shared__ ushort_t Kl[64][72];       // [k-col][dk]
    __shared__ ushort_t Vt[64][72];       // [dk][k-col] (transposed)
    __shared__ ushort_t Pl[4][32][72];    // per-wave P [q-row][k-col]

    const int tid  = threadIdx.x;
    const int lane = tid & 63;
    const int w    = tid >> 6;
    const int l15  = lane & 15, l4 = lane >> 4;
    const int qt   = blockIdx.x;
    const int bh   = blockIdx.y;
    const int b    = bh >> 4, h = bh & 15;
    const int q0   = qt * 128;
    const size_t headoff = (size_t)b * SS * DD + (size_t)h * DKK;

    // Q fragments straight from global (A-layout = 8 contiguous bf16)
    short8 qf[2][2];
    #pragma unroll
    for (int mi = 0; mi < 2; ++mi)
        #pragma unroll
        for (int ks = 0; ks < 2; ++ks) {
            int row = q0 + w * 32 + mi * 16 + l15;
            int dk  = ks * 32 + l4 * 8;
            qf[mi][ks] = *(const short8*)(Qp + headoff + (size_t)row * DD + dk);
        }

    float m_i[2][4], l_i[2][4];
    f32x4 O[2][4] = {};
    #pragma unroll
    for (int mi = 0; mi < 2; ++mi)
        #pragma unroll
        for (int r = 0; r < 4; ++r) { m_i[mi][r] = -__builtin_inff(); l_i[mi][r] = 0.f; }

    const int nkt = 2 * qt + 2;   // causal: tiles with k0 <= q0+127
    for (int kt = 0; kt < nkt; ++kt) {
        const int k0 = kt * 64;
        // ---- stage K tile [64][64] ----
        #pragma unroll
        for (int i = 0; i < 2; ++i) {
            int slot = tid + i * 256;                 // 0..511
            int row = slot >> 3, c = (slot & 7) * 8;
            *(short8*)(&Kl[row][c]) =
                *(const short8*)(Kp + headoff + (size_t)(k0 + row) * DD + c);
        }
        // ---- stage V transposed: Vt[dk][k] = V[k0+k][dk] ----
        #pragma unroll
        for (int i = 0; i < 2; ++i) {
            int slot = tid + i * 256;
            int row = slot >> 3, c = (slot & 7) * 8;
            short8 v = *(const short8*)(Vp + headoff + (size_t)(k0 + row) * DD + c);
            #pragma unroll
            for (int j = 0; j < 8; ++j) Vt[c + j][row] = (ushort_t)v[j];
        }
        __syncthreads();

        // ---- scores = Q * K^T ----
        short8 kf[4][2];
        #pragma unroll
        for (int ni = 0; ni < 4; ++ni)
            #pragma unroll
            for (int ks = 0; ks < 2; ++ks)
                kf[ni][ks] = *(const short8*)(&Kl[ni * 16 + l15][ks * 32 + l4 * 8]);

        f32x4 sc[2][4] = {};
        #pragma unroll
        for (int mi = 0; mi < 2; ++mi)
            #pragma unroll
            for (int ni = 0; ni < 4; ++ni)
                #pragma unroll
                for (int ks = 0; ks < 2; ++ks)
                    sc[mi][ni] = __builtin_amdgcn_mfma_f32_16x16x32_bf16(
                        qf[mi][ks], kf[ni][ks], sc[mi][ni], 0, 0, 0);

        // ---- scale + causal mask ----
        #pragma unroll
        for (int mi = 0; mi < 2; ++mi)
            #pragma unroll
            for (int ni = 0; ni < 4; ++ni)
                #pragma unroll
                for (int r = 0; r < 4; ++r) {
                    int kcol = k0 + ni * 16 + l15;
                    int qrow = q0 + w * 32 + mi * 16 + l4 * 4 + r;
                    float s  = sc[mi][ni][r] * 0.125f;   // 1/sqrt(64)
                    sc[mi][ni][r] = (kcol > qrow) ? -__builtin_inff() : s;
                }

        // ---- online softmax (rows live on 16-lane quads) ----
        #pragma unroll
        for (int mi = 0; mi < 2; ++mi)
            #pragma unroll
            for (int r = 0; r < 4; ++r) {
                float mx = sc[mi][0][r];
                #pragma unroll
                for (int ni = 1; ni < 4; ++ni) mx = fmaxf(mx, sc[mi][ni][r]);
                #pragma unroll
                for (int d = 1; d < 16; d <<= 1) mx = fmaxf(mx, __shfl_xor(mx, d, 64));
                float mnew  = fmaxf(m_i[mi][r], mx);
                float alpha = __expf(m_i[mi][r] - mnew);   // -inf case -> 0, never NaN
                float rs = 0.f;
                #pragma unroll
                for (int ni = 0; ni < 4; ++ni) {
                    float p = __expf(sc[mi][ni][r] - mnew);
                    sc[mi][ni][r] = p;
                    rs += p;
                }
                #pragma unroll
                for (int d = 1; d < 16; d <<= 1) rs += __shfl_xor(rs, d, 64);
                l_i[mi][r] = l_i[mi][r] * alpha + rs;
                m_i[mi][r] = mnew;
                #pragma unroll
                for (int nd = 0; nd < 4; ++nd) O[mi][nd][r] *= alpha;
            }

        // ---- P (C-layout) -> LDS -> A-layout ----
        #pragma unroll
        for (int mi = 0; mi < 2; ++mi)
            #pragma unroll
            for (int ni = 0; ni < 4; ++ni)
                #pragma unroll
                for (int r = 0; r < 4; ++r)
                    Pl[w][mi * 16 + l4 * 4 + r][ni * 16 + l15] = f2bf(sc[mi][ni][r]);
        // per-wave region: compiler inserts lgkmcnt for the write->read dep

        short8 pf[2][2], vf[2][4];
        #pragma unroll
        for (int mi = 0; mi < 2; ++mi)
            #pragma unroll
            for (int ks = 0; ks < 2; ++ks)
                pf[mi][ks] = *(const short8*)(&Pl[w][mi * 16 + l15][ks * 32 + l4 * 8]);
        #pragma unroll
        for (int ks = 0; ks < 2; ++ks)
            #pragma unroll
            for (int nd = 0; nd < 4; ++nd)
                vf[ks][nd] = *(const short8*)(&Vt[nd * 16 + l15][ks * 32 + l4 * 8]);

        #pragma unroll
        for (int mi = 0; mi < 2; ++mi)
            #pragma unroll
            for (int nd = 0; nd < 4; ++nd)
                #pragma unroll
                for (int ks = 0; ks < 2; ++ks)
                    O[mi][nd] = __builtin_amdgcn_mfma_f32_16x16x32_bf16(
                        pf[mi][ks], vf[ks][nd], O[mi][nd], 0, 0, 0);

        __syncthreads();   // protect Kl/Vt before next staging
    }

    // ---- epilogue: ctx = O / l ----
    #pragma unroll
    for (int mi = 0; mi < 2; ++mi)
        #pragma unroll
        for (int nd = 0; nd < 4; ++nd)
            #pragma unroll
            for (int r = 0; r < 4; ++r) {
                int row = q0 + w * 32 + mi * 16 + l4 * 4 + r;
                int dk  = nd * 16 + l15;
                float o = O[mi][nd][r] / l_i[mi][r];
                Ctx[headoff + (size_t)row * DD + dk] = f2bf(o);
            }
}

// ---------------------------------------------------------------------------
extern "C" void kernel_launch(void* const* d_in, const int* in_sizes, int n_in,
                              void* d_out, int out_size, void* d_ws, size_t ws_size,
                              hipStream_t stream)
{
    const float* q  = (const float*)d_in[0];
    const float* k  = (const float*)d_in[1];
    const float* v  = (const float*)d_in[2];
    const float* Wq = (const float*)d_in[3];
    const float* Wk = (const float*)d_in[4];
    const float* Wv = (const float*)d_in[5];
    const float* Wo = (const float*)d_in[6];
    // d_in[7] = mask: known-causal, handled analytically in attn_fwd
    float* out = (float*)d_out;

    // workspace: 4 bf16 buffers of [8192,1024] = 16.78 MB each (67.1 MB total)
    ushort_t* Qp  = (ushort_t*)d_ws;
    ushort_t* Kp  = Qp + (size_t)MTOT * DD;
    ushort_t* Vp  = Kp + (size_t)MTOT * DD;
    ushort_t* Ctx = Vp + (size_t)MTOT * DD;

    dim3 gg(MTOT / 128, DD / 128);   // (64, 8)
    gemm_bt<false, true><<<gg, 256, 0, stream>>>(q, Wq, Qp, DD, DD);
    gemm_bt<false, true><<<gg, 256, 0, stream>>>(k, Wk, Kp, DD, DD);
    gemm_bt<false, true><<<gg, 256, 0, stream>>>(v, Wv, Vp, DD, DD);

    attn_fwd<<<dim3(SS / 128, BB * HH), 256, 0, stream>>>(Qp, Kp, Vp, Ctx);

    gemm_bt<true, false><<<gg, 256, 0, stream>>>(Ctx, Wo, out, DD, DD);
}

// Round 2
// 389.507 us; speedup vs baseline: 2.1751x; 2.1751x over previous
//
#include <hip/hip_runtime.h>

// Problem constants: B=4, S=2048, D=1024, H=16, DK=64
#define BB 4
#define SS 2048
#define DD 1024
#define HH 16
#define DKK 64
#define MTOT (BB * SS)          // 8192
#define QKV_N (MTOT * DD)       // 8388608
#define W_N (DD * DD)           // 1048576

typedef __attribute__((ext_vector_type(8))) short short8;     // 8 bf16 (MFMA A/B frag)
typedef __attribute__((ext_vector_type(4))) float f32x4;      // MFMA C/D frag
typedef __attribute__((ext_vector_type(4))) unsigned short u16x4;
typedef unsigned short ushort_t;

#define GP(p) ((__attribute__((address_space(1))) void*)(p))
#define LP(p) ((__attribute__((address_space(3))) void*)(p))

__device__ __forceinline__ ushort_t f2bf(float f) {
    union { float f; unsigned u; } c; c.f = f;
    unsigned r = c.u + 0x7fffu + ((c.u >> 16) & 1u);   // RNE; inputs finite
    return (ushort_t)(r >> 16);
}

// ---------------------------------------------------------------------------
// fp32 -> bf16 convert, two segments fused (big tensor + weight matrix)
// ---------------------------------------------------------------------------
__global__ __launch_bounds__(256)
void cvt2(const float* __restrict__ s0, ushort_t* __restrict__ d0, int n0,
          const float* __restrict__ s1, ushort_t* __restrict__ d1, int n1)
{
    int i = (blockIdx.x * 256 + threadIdx.x) * 4;
    const float* s; ushort_t* d; int off;
    if (i < n0) { s = s0; d = d0; off = i; }
    else        { s = s1; d = d1; off = i - n0; if (off >= n1) return; }
    f32x4 x = *(const f32x4*)(s + off);
    u16x4 h;
    h[0] = f2bf(x[0]); h[1] = f2bf(x[1]); h[2] = f2bf(x[2]); h[3] = f2bf(x[3]);
    *(u16x4*)(d + off) = h;
}

// ---------------------------------------------------------------------------
// m97-style GEMM: C[M,N] = A[M,K] * W[N,K]^T, all bf16 in, M=8192 N=K=1024.
// 128x128 tile, BK=32, 4 waves (2x2), 64x64 per wave, 4x4 16x16x32 frags.
// Both operands staged with global_load_lds width=16, XOR-swizzled chunks
// (chunk = 16B; LDS slot c holds global (row=c>>2, cb=(c&3)^(row&3))).
// MODE 0: bf16 head-major [b,h,s,dk] (scale applied — Q gets 1/8)
// MODE 1: bf16 transposed [b,h,dk,s]  (V)
// MODE 2: fp32 row-major [M,N]        (final output)
// ---------------------------------------------------------------------------
template<int MODE>
__global__ __launch_bounds__(256, 2)
void gemm_m97(const ushort_t* __restrict__ A, const ushort_t* __restrict__ W,
              void* __restrict__ out, float scale)
{
    __shared__ ushort_t As[128 * 32];
    __shared__ ushort_t Bs[128 * 32];

    const int tid  = threadIdx.x;
    const int lane = tid & 63;
    const int w    = tid >> 6;
    const int wm   = w >> 1, wn = w & 1;
    const int l15  = lane & 15, l4 = lane >> 4;
    const int m0   = blockIdx.x * 128;
    const int n0   = blockIdx.y * 128;

    f32x4 acc[4][4] = {};

    for (int kk = 0; kk < 1024; kk += 32) {
        #pragma unroll
        for (int i = 0; i < 2; ++i) {
            int c  = i * 256 + w * 64 + lane;          // LDS chunk id 0..511
            int r  = c >> 2;
            int cb = (c & 3) ^ (r & 3);                // swizzled global chunk
            __builtin_amdgcn_global_load_lds(
                GP(A + (size_t)(m0 + r) * 1024 + kk + cb * 8), LP(As + c * 8), 16, 0, 0);
            __builtin_amdgcn_global_load_lds(
                GP(W + (size_t)(n0 + r) * 1024 + kk + cb * 8), LP(Bs + c * 8), 16, 0, 0);
        }
        __syncthreads();

        short8 af[4], bfr[4];
        #pragma unroll
        for (int mi = 0; mi < 4; ++mi) {
            int row = wm * 64 + mi * 16 + l15;
            af[mi] = *(const short8*)(As + (row * 4 + (l4 ^ (row & 3))) * 8);
        }
        #pragma unroll
        for (int ni = 0; ni < 4; ++ni) {
            int row = wn * 64 + ni * 16 + l15;
            bfr[ni] = *(const short8*)(Bs + (row * 4 + (l4 ^ (row & 3))) * 8);
        }
        #pragma unroll
        for (int mi = 0; mi < 4; ++mi)
            #pragma unroll
            for (int ni = 0; ni < 4; ++ni)
                acc[mi][ni] = __builtin_amdgcn_mfma_f32_16x16x32_bf16(
                    af[mi], bfr[ni], acc[mi][ni], 0, 0, 0);
        __syncthreads();
    }

    // ---- epilogue (C/D: col=lane&15, row=(lane>>4)*4+r) ----
    #pragma unroll
    for (int mi = 0; mi < 4; ++mi) {
        int rowb = m0 + wm * 64 + mi * 16 + l4 * 4;
        #pragma unroll
        for (int ni = 0; ni < 4; ++ni) {
            int n = n0 + wn * 64 + ni * 16 + l15;
            if constexpr (MODE == 0) {
                int h = n >> 6, dk = n & 63;
                #pragma unroll
                for (int r = 0; r < 4; ++r) {
                    int m = rowb + r, b = m >> 11, s = m & 2047;
                    ((ushort_t*)out)[(((size_t)(b * 16 + h) * 2048 + s) << 6) + dk] =
                        f2bf(acc[mi][ni][r] * scale);
                }
            } else if constexpr (MODE == 1) {
                int h = n >> 6, dk = n & 63;
                int b = rowb >> 11, s0v = rowb & 2047;   // 4 r's share b (128-aligned tiles)
                u16x4 hh;
                #pragma unroll
                for (int r = 0; r < 4; ++r) hh[r] = f2bf(acc[mi][ni][r]);
                *(u16x4*)((ushort_t*)out + (((size_t)(b * 16 + h) << 6) + dk) * 2048 + s0v) = hh;
            } else {
                #pragma unroll
                for (int r = 0; r < 4; ++r)
                    ((float*)out)[(size_t)(rowb + r) * 1024 + n] = acc[mi][ni][r];
            }
        }
    }
}

// ---------------------------------------------------------------------------
// Flash-style causal attention. Q,K head-major [b,h,s,dk]; V transposed
// [b,h,dk,s]; all bf16, Q pre-scaled by 1/8. 128 q-rows/block (32/wave),
// k-tiles of 64. K/V staged via global_load_lds with XOR swizzle.
// Heavy-diagonal-first block order. Ctx out: bf16 [b,s,d].
// ---------------------------------------------------------------------------
__global__ __launch_bounds__(256, 2)
void attn_fwd2(const ushort_t* __restrict__ Qh, const ushort_t* __restrict__ Kh,
               const ushort_t* __restrict__ Vt, ushort_t* __restrict__ Ctx)
{
    __shared__ ushort_t Kl[64 * 64];      // swizzled 16B chunks
    __shared__ ushort_t Vl[64 * 64];      // swizzled 16B chunks
    __shared__ ushort_t Pl[4][32][72];    // per-wave P [q-row][k-col], +8 pad

    const int tid  = threadIdx.x;
    const int lane = tid & 63;
    const int w    = tid >> 6;
    const int l15  = lane & 15, l4 = lane >> 4;
    const int idx  = blockIdx.x;
    const int qt   = 15 - (idx >> 6);     // heavy q-tiles first
    const int bh   = idx & 63;
    const int b    = bh >> 4, h = bh & 15;
    const int q0   = qt * 128;
    const ushort_t* Qb = Qh + (size_t)bh * SS * DKK;
    const ushort_t* Kb = Kh + (size_t)bh * SS * DKK;
    const ushort_t* Vb = Vt + (size_t)bh * DKK * SS;

    // Q fragments straight from global (A-layout: m=l15 row, k contiguous)
    short8 qf[2][2];
    #pragma unroll
    for (int mi = 0; mi < 2; ++mi)
        #pragma unroll
        for (int ks = 0; ks < 2; ++ks) {
            int row = q0 + w * 32 + mi * 16 + l15;
            qf[mi][ks] = *(const short8*)(Qb + (size_t)row * 64 + ks * 32 + l4 * 8);
        }

    float m_i[2][4], l_i[2][4];
    f32x4 O[2][4] = {};
    #pragma unroll
    for (int mi = 0; mi < 2; ++mi)
        #pragma unroll
        for (int r = 0; r < 4; ++r) { m_i[mi][r] = -__builtin_inff(); l_i[mi][r] = 0.f; }

    const int nkt = 2 * qt + 2;
    for (int kt = 0; kt < nkt; ++kt) {
        const int k0 = kt * 64;
        // ---- stage K [64 s][64 dk] and V [64 dk][64 s] tiles, swizzled ----
        #pragma unroll
        for (int i = 0; i < 2; ++i) {
            int c  = i * 256 + w * 64 + lane;          // 0..511
            int r  = c >> 3;
            int cb = (c & 7) ^ (r & 7);
            __builtin_amdgcn_global_load_lds(
                GP(Kb + (size_t)(k0 + r) * 64 + cb * 8), LP(Kl + c * 8), 16, 0, 0);
            __builtin_amdgcn_global_load_lds(
                GP(Vb + (size_t)r * 2048 + k0 + cb * 8), LP(Vl + c * 8), 16, 0, 0);
        }
        __syncthreads();

        // ---- scores = Q * K^T (Q pre-scaled) ----
        short8 kf[4][2];
        #pragma unroll
        for (int ni = 0; ni < 4; ++ni)
            #pragma unroll
            for (int ks = 0; ks < 2; ++ks) {
                int r = ni * 16 + l15, cb = ks * 4 + l4;
                kf[ni][ks] = *(const short8*)(Kl + (r * 8 + (cb ^ (r & 7))) * 8);
            }

        f32x4 sc[2][4] = {};
        #pragma unroll
        for (int mi = 0; mi < 2; ++mi)
            #pragma unroll
            for (int ni = 0; ni < 4; ++ni)
                #pragma unroll
                for (int ks = 0; ks < 2; ++ks)
                    sc[mi][ni] = __builtin_amdgcn_mfma_f32_16x16x32_bf16(
                        qf[mi][ks], kf[ni][ks], sc[mi][ni], 0, 0, 0);

        // ---- causal mask ----
        #pragma unroll
        for (int mi = 0; mi < 2; ++mi)
            #pragma unroll
            for (int ni = 0; ni < 4; ++ni)
                #pragma unroll
                for (int r = 0; r < 4; ++r) {
                    int kcol = k0 + ni * 16 + l15;
                    int qrow = q0 + w * 32 + mi * 16 + l4 * 4 + r;
                    if (kcol > qrow) sc[mi][ni][r] = -__builtin_inff();
                }

        // ---- online softmax (row = fixed (l4,r), cols across 16 l15 lanes) ----
        #pragma unroll
        for (int mi = 0; mi < 2; ++mi)
            #pragma unroll
            for (int r = 0; r < 4; ++r) {
                float mx = sc[mi][0][r];
                #pragma unroll
                for (int ni = 1; ni < 4; ++ni) mx = fmaxf(mx, sc[mi][ni][r]);
                #pragma unroll
                for (int d = 1; d < 16; d <<= 1) mx = fmaxf(mx, __shfl_xor(mx, d, 64));
                float mnew  = fmaxf(m_i[mi][r], mx);
                float alpha = __expf(m_i[mi][r] - mnew);
                float rs = 0.f;
                #pragma unroll
                for (int ni = 0; ni < 4; ++ni) {
                    float p = __expf(sc[mi][ni][r] - mnew);
                    sc[mi][ni][r] = p;
                    rs += p;
                }
                #pragma unroll
                for (int d = 1; d < 16; d <<= 1) rs += __shfl_xor(rs, d, 64);
                l_i[mi][r] = l_i[mi][r] * alpha + rs;
                m_i[mi][r] = mnew;
                #pragma unroll
                for (int nd = 0; nd < 4; ++nd) O[mi][nd][r] *= alpha;
            }

        // ---- P (C-layout) -> per-wave LDS -> A-layout frags ----
        #pragma unroll
        for (int mi = 0; mi < 2; ++mi)
            #pragma unroll
            for (int ni = 0; ni < 4; ++ni)
                #pragma unroll
                for (int r = 0; r < 4; ++r)
                    Pl[w][mi * 16 + l4 * 4 + r][ni * 16 + l15] = f2bf(sc[mi][ni][r]);

        short8 pf[2][2], vf[2][4];
        #pragma unroll
        for (int mi = 0; mi < 2; ++mi)
            #pragma unroll
            for (int ks = 0; ks < 2; ++ks)
                pf[mi][ks] = *(const short8*)(&Pl[w][mi * 16 + l15][ks * 32 + l4 * 8]);
        #pragma unroll
        for (int ks = 0; ks < 2; ++ks)
            #pragma unroll
            for (int nd = 0; nd < 4; ++nd) {
                int r = nd * 16 + l15, cb = ks * 4 + l4;
                vf[ks][nd] = *(const short8*)(Vl + (r * 8 + (cb ^ (r & 7))) * 8);
            }

        #pragma unroll
        for (int mi = 0; mi < 2; ++mi)
            #pragma unroll
            for (int nd = 0; nd < 4; ++nd)
                #pragma unroll
                for (int ks = 0; ks < 2; ++ks)
                    O[mi][nd] = __builtin_amdgcn_mfma_f32_16x16x32_bf16(
                        pf[mi][ks], vf[ks][nd], O[mi][nd], 0, 0, 0);

        __syncthreads();   // protect Kl/Vl for next k-tile
    }

    // ---- epilogue: Ctx[b,s,d] bf16 ----
    #pragma unroll
    for (int mi = 0; mi < 2; ++mi)
        #pragma unroll
        for (int nd = 0; nd < 4; ++nd)
            #pragma unroll
            for (int r = 0; r < 4; ++r) {
                int row = q0 + w * 32 + mi * 16 + l4 * 4 + r;
                int dk  = nd * 16 + l15;
                float o = O[mi][nd][r] / l_i[mi][r];
                Ctx[((size_t)b * 2048 + row) * 1024 + h * 64 + dk] = f2bf(o);
            }
}

// ---------------------------------------------------------------------------
extern "C" void kernel_launch(void* const* d_in, const int* in_sizes, int n_in,
                              void* d_out, int out_size, void* d_ws, size_t ws_size,
                              hipStream_t stream)
{
    const float* q  = (const float*)d_in[0];
    const float* k  = (const float*)d_in[1];
    const float* v  = (const float*)d_in[2];
    const float* Wq = (const float*)d_in[3];
    const float* Wk = (const float*)d_in[4];
    const float* Wv = (const float*)d_in[5];
    const float* Wo = (const float*)d_in[6];
    float* out = (float*)d_out;

    // workspace: 4 x 16.78 MB bf16 buffers = 67.1 MB (same footprint as R1)
    ushort_t* B0 = (ushort_t*)d_ws;            // cvt scratch, later Ctx
    ushort_t* B1 = B0 + (size_t)QKV_N;         // Qh, later Wo-bf16 scratch
    ushort_t* B2 = B1 + (size_t)QKV_N;         // Kh
    ushort_t* B3 = B2 + (size_t)QKV_N;         // Vt [b,h,dk,s]
    ushort_t* wbE = (ushort_t*)d_out;          // 2 MB W scratch inside out buf
                                               // (final GEMM overwrites all)
    dim3 gg(MTOT / 128, DD / 128);             // (64, 8)
    const int cvtg = (QKV_N + W_N) / 1024;     // 9216

    cvt2<<<cvtg, 256, 0, stream>>>(q, B0, QKV_N, Wq, wbE, W_N);
    gemm_m97<0><<<gg, 256, 0, stream>>>(B0, wbE, B1, 0.125f);   // Q, pre-scaled

    cvt2<<<cvtg, 256, 0, stream>>>(k, B0, QKV_N, Wk, wbE, W_N);
    gemm_m97<0><<<gg, 256, 0, stream>>>(B0, wbE, B2, 1.0f);     // K

    cvt2<<<cvtg, 256, 0, stream>>>(v, B0, QKV_N, Wv, wbE, W_N);
    gemm_m97<1><<<gg, 256, 0, stream>>>(B0, wbE, B3, 1.0f);     // V transposed

    attn_fwd2<<<1024, 256, 0, stream>>>(B1, B2, B3, B0);        // Ctx -> B0

    cvt2<<<W_N / 1024, 256, 0, stream>>>(Wo, B1, W_N, Wo, B1, 0);
    gemm_m97<2><<<gg, 256, 0, stream>>>(B0, B1, out, 1.0f);     // final fp32
}